// Round 2
// baseline (478.765 us; speedup 1.0000x reference)
//
#include <hip/hip_runtime.h>
#include <stdint.h>

// ---------------------------------------------------------------------------
// GQA forward: y = OutProj( Attention( QKVProj(x) ) )
// B=2, S=2048, EMB=2048, NQH=16, HD=128, NKV=4, G=4. Full (non-causal) softmax:
// the reference ignores attn_mask / is_causal.
// Strategy: cast to bf16, MFMA 16x16x32 GEMMs (m97 structure), flash-style
// attention with online softmax. V is written transposed by the QKV GEMM
// epilogue so PV B-fragments are contiguous ds_read_b128.
// R1: resubmit of R0 (container infra failure — no kernel signal).
// ---------------------------------------------------------------------------

typedef short s8v __attribute__((ext_vector_type(8)));   // 8 bf16 = 16 B
typedef float f4  __attribute__((ext_vector_type(4)));
typedef unsigned short u16;

#define GLD_LDS(g, l) __builtin_amdgcn_global_load_lds(                     \
    (const __attribute__((address_space(1))) void*)(g),                     \
    (__attribute__((address_space(3))) void*)(l), 16, 0, 0)

__device__ __forceinline__ u16 f2bf(float f) {
    union { float f; uint32_t u; } v; v.f = f;
    uint32_t u = v.u;
    return (u16)((u + 0x7fffu + ((u >> 16) & 1u)) >> 16);   // RNE
}

// --------------------------- fp32 -> bf16 cast ------------------------------
__global__ void cvt_kernel(const float* __restrict__ src, u16* __restrict__ dst, int n4) {
    int i = blockIdx.x * blockDim.x + threadIdx.x;
    if (i >= n4) return;
    float4 v = ((const float4*)src)[i];
    ushort4 o;
    o.x = f2bf(v.x); o.y = f2bf(v.y); o.z = f2bf(v.z); o.w = f2bf(v.w);
    ((ushort4*)dst)[i] = o;
}

// --------------------------- GEMM: C = A * B^T ------------------------------
// A: [M,K] bf16 row-major.  Bm: [N,K] bf16 row-major (torch Linear weight).
// MODE 0: QKV epilogue -> qkOut [M,2560] bf16 (cols 0..2047 Q, 2048..2559 K),
//         V (cols 2560..3071) written transposed to vtOut [(b*4+h)*128+d][2048].
// MODE 1: fp32 epilogue -> fOut [M,N].
// 128x128 block, BK=32, 4 waves (2x2), 4x4 16x16 tiles/wave.
// Staging via global_load_lds(16B); XOR swizzle applied on the GLOBAL source
// address (LDS dest must stay contiguous) to reduce ds_read_b128 conflicts.
template<int MODE>
__global__ __launch_bounds__(256, 2)
void gemm_bt(const u16* __restrict__ A, const u16* __restrict__ Bm,
             int M, int N, int K,
             u16* __restrict__ qkOut, u16* __restrict__ vtOut,
             float* __restrict__ fOut)
{
    __shared__ __attribute__((aligned(16))) u16 As[128 * 32];
    __shared__ __attribute__((aligned(16))) u16 Bs[128 * 32];

    const int tid  = threadIdx.x;
    const int wave = tid >> 6, lane = tid & 63;
    const int quad = lane >> 4, l16 = lane & 15;
    const int wr = wave >> 1, wc = wave & 1;
    const int m0 = blockIdx.y * 128, n0 = blockIdx.x * 128;

    const int rowC = lane >> 2;   // 0..15 row within a 16-row staging chunk
    const int slot = lane & 3;    // 16B slot within 64B row

    f4 acc[4][4] = {};

    for (int k0 = 0; k0 < K; k0 += 32) {
        #pragma unroll
        for (int i = 0; i < 4; i++) {
            const int c  = wave + i * 4;          // 0..15, wave-uniform
            const int ch = c & 7;
            const int row = ch * 16 + rowC;
            const int glog = slot ^ (row & 3);    // source-side XOR swizzle
            const u16* gsrc = (c < 8)
                ? (A  + (size_t)(m0 + row) * K + k0 + glog * 8)
                : (Bm + (size_t)(n0 + row) * K + k0 + glog * 8);
            u16* lbase = (c < 8) ? (As + ch * 512) : (Bs + ch * 512);
            GLD_LDS(gsrc, lbase);
        }
        __syncthreads();   // compiler drains vmcnt before s_barrier

        s8v af[4], bfr[4];
        #pragma unroll
        for (int t = 0; t < 4; t++) {
            int row = wr * 64 + t * 16 + l16;
            af[t] = *(const s8v*)(As + row * 32 + ((quad ^ (row & 3)) * 8));
        }
        #pragma unroll
        for (int u = 0; u < 4; u++) {
            int row = wc * 64 + u * 16 + l16;
            bfr[u] = *(const s8v*)(Bs + row * 32 + ((quad ^ (row & 3)) * 8));
        }
        #pragma unroll
        for (int t = 0; t < 4; t++)
            #pragma unroll
            for (int u = 0; u < 4; u++)
                acc[t][u] = __builtin_amdgcn_mfma_f32_16x16x32_bf16(
                    af[t], bfr[u], acc[t][u], 0, 0, 0);
        __syncthreads();
    }

    // Epilogue. D layout: row = quad*4+reg, col = l16 (m89/m91-verified).
    if (MODE == 0) {
        if (n0 < 2560) {           // Q / K region (2560 % 128 == 0 -> uniform)
            #pragma unroll
            for (int t = 0; t < 4; t++) {
                int gm0 = m0 + wr * 64 + t * 16 + quad * 4;
                #pragma unroll
                for (int u = 0; u < 4; u++) {
                    int gn = n0 + wc * 64 + u * 16 + l16;
                    #pragma unroll
                    for (int r = 0; r < 4; r++)
                        qkOut[(size_t)(gm0 + r) * 2560 + gn] = f2bf(acc[t][u][r]);
                }
            }
        } else {                   // V region -> transposed store, 4 s packed
            #pragma unroll
            for (int t = 0; t < 4; t++) {
                int gm0 = m0 + wr * 64 + t * 16 + quad * 4;
                int bb = gm0 >> 11, s = gm0 & 2047;
                #pragma unroll
                for (int u = 0; u < 4; u++) {
                    int gn = n0 + wc * 64 + u * 16 + l16;
                    int dd = gn - 2560;
                    ushort4 pk;
                    pk.x = f2bf(acc[t][u][0]); pk.y = f2bf(acc[t][u][1]);
                    pk.z = f2bf(acc[t][u][2]); pk.w = f2bf(acc[t][u][3]);
                    *(ushort4*)(vtOut +
                        ((size_t)(bb * 4 + (dd >> 7)) * 128 + (dd & 127)) * 2048 + s) = pk;
                }
            }
        }
    } else {
        #pragma unroll
        for (int t = 0; t < 4; t++) {
            int gm0 = m0 + wr * 64 + t * 16 + quad * 4;
            #pragma unroll
            for (int u = 0; u < 4; u++) {
                int gn = n0 + wc * 64 + u * 16 + l16;
                #pragma unroll
                for (int r = 0; r < 4; r++)
                    fOut[(size_t)(gm0 + r) * N + gn] = acc[t][u][r];
            }
        }
    }
}

// ------------------------------- attention ----------------------------------
// Block: 128 q-rows (2 m-tiles of 16 per wave, 4 waves), KV tiles of 32.
// qk: [4096, 2560] bf16 (Q | K).  vt: [(b*4+h)*128+d][2048] bf16.
// ao: [4096, 2048] bf16 attention output (head-major cols hf*128+d).
__global__ __launch_bounds__(256, 2)
void attn_kernel(const u16* __restrict__ qk, const u16* __restrict__ vt,
                 u16* __restrict__ ao)
{
    __shared__ __attribute__((aligned(16))) u16 Ks[32 * 136];   // +8 pad
    __shared__ __attribute__((aligned(16))) u16 Vs[128 * 40];   // +8 pad
    __shared__ __attribute__((aligned(16))) u16 Ps[4][2][640];  // per-wave P

    const int tid  = threadIdx.x;
    const int wave = tid >> 6, lane = tid & 63;
    const int quad = lane >> 4, l16 = lane & 15;
    const int bh = blockIdx.y;
    const int b = bh >> 4, hf = bh & 15, h = hf >> 2;
    const int i0 = blockIdx.x * 128;

    // Q fragments (A-operand: A[m=l16][k=quad*8+j], k-chunks of 32)
    s8v aq[2][4];
    #pragma unroll
    for (int mt = 0; mt < 2; mt++) {
        const u16* qrow = qk + (size_t)(b * 2048 + i0 + mt * 64 + wave * 16 + l16) * 2560
                             + hf * 128 + quad * 8;
        #pragma unroll
        for (int c4 = 0; c4 < 4; c4++) aq[mt][c4] = *(const s8v*)(qrow + c4 * 32);
    }

    float m_i[2][4], l_i[2][4];
    f4 o[2][8] = {};
    #pragma unroll
    for (int mt = 0; mt < 2; mt++)
        #pragma unroll
        for (int r = 0; r < 4; r++) { m_i[mt][r] = -1e30f; l_i[mt][r] = 0.f; }

    const u16* kbase = qk + (size_t)(b * 2048) * 2560 + 2048 + h * 128;
    const u16* vbase = vt + (size_t)((b * 4 + h) * 128) * 2048;

    for (int s0 = 0; s0 < 2048; s0 += 32) {
        // stage K (32x128 -> stride 136) and V^T (128x32 -> stride 40)
        #pragma unroll
        for (int it = 0; it < 2; it++) {
            int idx = it * 256 + tid;                 // 0..511
            int row = idx >> 4, g = idx & 15;
            *(s8v*)(Ks + row * 136 + g * 8) =
                *(const s8v*)(kbase + (size_t)(s0 + row) * 2560 + g * 8);
            int d = idx >> 2, sg = idx & 3;
            *(s8v*)(Vs + d * 40 + sg * 8) =
                *(const s8v*)(vbase + (size_t)d * 2048 + s0 + sg * 8);
        }
        __syncthreads();

        // S = Q K^T  (two 16-col groups)
        f4 sc[2][2] = {};
        #pragma unroll
        for (int c4 = 0; c4 < 4; c4++)
            #pragma unroll
            for (int cg = 0; cg < 2; cg++) {
                s8v bk = *(const s8v*)(Ks + (cg * 16 + l16) * 136 + c4 * 32 + quad * 8);
                #pragma unroll
                for (int mt = 0; mt < 2; mt++)
                    sc[mt][cg] = __builtin_amdgcn_mfma_f32_16x16x32_bf16(
                        aq[mt][c4], bk, sc[mt][cg], 0, 0, 0);
            }

        // online softmax (rows live in quads; reduce over 16 lanes)
        #pragma unroll
        for (int mt = 0; mt < 2; mt++) {
            float mx[4], al[4], rs[4];
            #pragma unroll
            for (int r = 0; r < 4; r++) {
                sc[mt][0][r] *= 0.08838834764831845f;   // 1/sqrt(128)
                sc[mt][1][r] *= 0.08838834764831845f;
                mx[r] = fmaxf(sc[mt][0][r], sc[mt][1][r]);
            }
            #pragma unroll
            for (int off = 1; off < 16; off <<= 1)
                #pragma unroll
                for (int r = 0; r < 4; r++) mx[r] = fmaxf(mx[r], __shfl_xor(mx[r], off));
            #pragma unroll
            for (int r = 0; r < 4; r++) {
                float mn = fmaxf(m_i[mt][r], mx[r]);
                al[r] = __expf(m_i[mt][r] - mn);
                m_i[mt][r] = mn;
                sc[mt][0][r] = __expf(sc[mt][0][r] - mn);
                sc[mt][1][r] = __expf(sc[mt][1][r] - mn);
                rs[r] = sc[mt][0][r] + sc[mt][1][r];
            }
            #pragma unroll
            for (int off = 1; off < 16; off <<= 1)
                #pragma unroll
                for (int r = 0; r < 4; r++) rs[r] += __shfl_xor(rs[r], off);
            f4 al4 = {al[0], al[1], al[2], al[3]};
            #pragma unroll
            for (int r = 0; r < 4; r++) l_i[mt][r] = l_i[mt][r] * al[r] + rs[r];
            #pragma unroll
            for (int ch = 0; ch < 8; ch++) o[mt][ch] *= al4;
            // P: C-layout -> LDS (row = quad*4+r, col = cg*16+l16)
            #pragma unroll
            for (int cg = 0; cg < 2; cg++)
                #pragma unroll
                for (int r = 0; r < 4; r++)
                    Ps[wave][mt][(quad * 4 + r) * 40 + cg * 16 + l16] = f2bf(sc[mt][cg][r]);
        }
        __syncthreads();   // safety: P write -> A-layout read (remove later)

        // O += P V : P as A-operand, V^T rows as B-operand (contiguous k)
        s8v ap0 = *(const s8v*)(&Ps[wave][0][l16 * 40 + quad * 8]);
        s8v ap1 = *(const s8v*)(&Ps[wave][1][l16 * 40 + quad * 8]);
        #pragma unroll
        for (int ch = 0; ch < 8; ch++) {
            s8v bv = *(const s8v*)(Vs + (ch * 16 + l16) * 40 + quad * 8);
            o[0][ch] = __builtin_amdgcn_mfma_f32_16x16x32_bf16(ap0, bv, o[0][ch], 0, 0, 0);
            o[1][ch] = __builtin_amdgcn_mfma_f32_16x16x32_bf16(ap1, bv, o[1][ch], 0, 0, 0);
        }
        __syncthreads();   // protect Ks/Vs before next staging
    }

    #pragma unroll
    for (int mt = 0; mt < 2; mt++)
        #pragma unroll
        for (int r = 0; r < 4; r++) {
            float inv = 1.f / l_i[mt][r];
            int gm = b * 2048 + i0 + mt * 64 + wave * 16 + quad * 4 + r;
            #pragma unroll
            for (int ch = 0; ch < 8; ch++) {
                int gn = hf * 128 + ch * 16 + l16;
                ao[(size_t)gm * 2048 + gn] = f2bf(o[mt][ch][r] * inv);
            }
        }
}

// ------------------------------- launcher -----------------------------------
extern "C" void kernel_launch(void* const* d_in, const int* in_sizes, int n_in,
                              void* d_out, int out_size, void* d_ws, size_t ws_size,
                              hipStream_t stream)
{
    const float* x  = (const float*)d_in[0];
    // d_in[1] = attn_mask (unused), d_in[2] = is_causal (unused by reference)
    const float* Wq = (const float*)d_in[3];
    const float* Wk = (const float*)d_in[4];
    const float* Wv = (const float*)d_in[5];
    const float* Wo = (const float*)d_in[6];

    char* ws = (char*)d_ws;
    // byte offsets (all 256-aligned)
    u16* xb   = (u16*)(ws);                 // 4096x2048       16,777,216 B
    u16* wqkv = (u16*)(ws + 16777216);      // 3072x2048       12,582,912 B
    u16* wo   = (u16*)(ws + 29360128);      // 2048x2048        8,388,608 B
    u16* qkb  = (u16*)(ws + 37748736);      // 4096x2560       20,971,520 B
    u16* vtb  = (u16*)(ws + 58720256);      // 2x4x128x2048     4,194,304 B
    u16* ao   = (u16*)(ws + 62914560);      // 4096x2048       16,777,216 B
    if (ws_size < 79691776u) return;        // workspace too small -> fail loud

    // fp32 -> bf16 (Wq|Wk|Wv concatenated along out-features)
    cvt_kernel<<<8192, 256, 0, stream>>>(x,  xb,             2097152);
    cvt_kernel<<<4096, 256, 0, stream>>>(Wq, wqkv,           1048576);
    cvt_kernel<<<1024, 256, 0, stream>>>(Wk, wqkv + 4194304,  262144);
    cvt_kernel<<<1024, 256, 0, stream>>>(Wv, wqkv + 5242880,  262144);
    cvt_kernel<<<4096, 256, 0, stream>>>(Wo, wo,             1048576);

    // fused QKV projection: [4096,2048] x [3072,2048]^T
    gemm_bt<0><<<dim3(24, 32), 256, 0, stream>>>(xb, wqkv, 4096, 3072, 2048,
                                                 qkb, vtb, nullptr);
    // attention: grid = (S/128, B*NQH)
    attn_kernel<<<dim3(16, 32), 256, 0, stream>>>(qkb, vtb, ao);
    // output projection -> fp32 d_out
    gemm_bt<1><<<dim3(16, 32), 256, 0, stream>>>(ao, wo, 4096, 2048, 2048,
                                                 nullptr, nullptr, (float*)d_out);
}

// Round 3
// 403.944 us; speedup vs baseline: 1.1852x; 1.1852x over previous
//
#include <hip/hip_runtime.h>
#include <stdint.h>

// ---------------------------------------------------------------------------
// GQA forward: y = OutProj( Attention( QKVProj(x) ) )
// B=2, S=2048, EMB=2048, NQH=16, HD=128, NKV=4, G=4. Non-causal softmax.
// R3: attention rework — Q-tile 64 (1 m-tile/wave, grid 1024 = 4 blk/CU),
//     KV-tile 64, global_load_lds staging with XOR swizzle (unpadded LDS),
//     col-group-first softmax reduction, no P barrier, Q pre-scaled in GEMM.
// ---------------------------------------------------------------------------

typedef short s8v __attribute__((ext_vector_type(8)));   // 8 bf16 = 16 B
typedef float f4  __attribute__((ext_vector_type(4)));
typedef unsigned short u16;

#define GLD_LDS(g, l) __builtin_amdgcn_global_load_lds(                     \
    (const __attribute__((address_space(1))) void*)(g),                     \
    (__attribute__((address_space(3))) void*)(l), 16, 0, 0)

__device__ __forceinline__ u16 f2bf(float f) {
    union { float f; uint32_t u; } v; v.f = f;
    uint32_t u = v.u;
    return (u16)((u + 0x7fffu + ((u >> 16) & 1u)) >> 16);   // RNE
}

// --------------------------- fp32 -> bf16 cast ------------------------------
__global__ void cvt_kernel(const float* __restrict__ src, u16* __restrict__ dst, int n4) {
    int i = blockIdx.x * blockDim.x + threadIdx.x;
    if (i >= n4) return;
    float4 v = ((const float4*)src)[i];
    ushort4 o;
    o.x = f2bf(v.x); o.y = f2bf(v.y); o.z = f2bf(v.z); o.w = f2bf(v.w);
    ((ushort4*)dst)[i] = o;
}

// --------------------------- GEMM: C = A * B^T ------------------------------
// MODE 0: QKV epilogue -> qkOut [M,2560] (Q cols pre-scaled by 1/sqrt(128)),
//         V cols written transposed to vtOut [(b*4+h)*128+d][2048].
// MODE 1: fp32 epilogue -> fOut [M,N].
template<int MODE>
__global__ __launch_bounds__(256, 2)
void gemm_bt(const u16* __restrict__ A, const u16* __restrict__ Bm,
             int M, int N, int K,
             u16* __restrict__ qkOut, u16* __restrict__ vtOut,
             float* __restrict__ fOut)
{
    __shared__ __attribute__((aligned(16))) u16 As[128 * 32];
    __shared__ __attribute__((aligned(16))) u16 Bs[128 * 32];

    const int tid  = threadIdx.x;
    const int wave = tid >> 6, lane = tid & 63;
    const int quad = lane >> 4, l16 = lane & 15;
    const int wr = wave >> 1, wc = wave & 1;
    const int m0 = blockIdx.y * 128, n0 = blockIdx.x * 128;

    const int rowC = lane >> 2;   // 0..15 row within a 16-row staging chunk
    const int slot = lane & 3;    // 16B slot within 64B row

    f4 acc[4][4] = {};

    for (int k0 = 0; k0 < K; k0 += 32) {
        #pragma unroll
        for (int i = 0; i < 4; i++) {
            const int c  = wave + i * 4;          // wave-uniform chunk
            const int ch = c & 7;
            const int row = ch * 16 + rowC;
            const int glog = slot ^ (row & 3);    // source-side XOR swizzle
            const u16* gsrc = (c < 8)
                ? (A  + (size_t)(m0 + row) * K + k0 + glog * 8)
                : (Bm + (size_t)(n0 + row) * K + k0 + glog * 8);
            u16* lbase = (c < 8) ? (As + ch * 512) : (Bs + ch * 512);
            GLD_LDS(gsrc, lbase);
        }
        __syncthreads();

        s8v af[4], bfr[4];
        #pragma unroll
        for (int t = 0; t < 4; t++) {
            int row = wr * 64 + t * 16 + l16;
            af[t] = *(const s8v*)(As + row * 32 + ((quad ^ (row & 3)) * 8));
        }
        #pragma unroll
        for (int u = 0; u < 4; u++) {
            int row = wc * 64 + u * 16 + l16;
            bfr[u] = *(const s8v*)(Bs + row * 32 + ((quad ^ (row & 3)) * 8));
        }
        #pragma unroll
        for (int t = 0; t < 4; t++)
            #pragma unroll
            for (int u = 0; u < 4; u++)
                acc[t][u] = __builtin_amdgcn_mfma_f32_16x16x32_bf16(
                    af[t], bfr[u], acc[t][u], 0, 0, 0);
        __syncthreads();
    }

    // Epilogue. D layout: row = quad*4+reg, col = l16.
    if (MODE == 0) {
        if (n0 < 2560) {           // Q / K region
            const float qs = (n0 < 2048) ? 0.08838834764831845f : 1.0f;
            #pragma unroll
            for (int t = 0; t < 4; t++) {
                int gm0 = m0 + wr * 64 + t * 16 + quad * 4;
                #pragma unroll
                for (int u = 0; u < 4; u++) {
                    int gn = n0 + wc * 64 + u * 16 + l16;
                    #pragma unroll
                    for (int r = 0; r < 4; r++)
                        qkOut[(size_t)(gm0 + r) * 2560 + gn] = f2bf(acc[t][u][r] * qs);
                }
            }
        } else {                   // V region -> transposed store
            #pragma unroll
            for (int t = 0; t < 4; t++) {
                int gm0 = m0 + wr * 64 + t * 16 + quad * 4;
                int bb = gm0 >> 11, s = gm0 & 2047;
                #pragma unroll
                for (int u = 0; u < 4; u++) {
                    int gn = n0 + wc * 64 + u * 16 + l16;
                    int dd = gn - 2560;
                    ushort4 pk;
                    pk.x = f2bf(acc[t][u][0]); pk.y = f2bf(acc[t][u][1]);
                    pk.z = f2bf(acc[t][u][2]); pk.w = f2bf(acc[t][u][3]);
                    *(ushort4*)(vtOut +
                        ((size_t)(bb * 4 + (dd >> 7)) * 128 + (dd & 127)) * 2048 + s) = pk;
                }
            }
        }
    } else {
        #pragma unroll
        for (int t = 0; t < 4; t++) {
            int gm0 = m0 + wr * 64 + t * 16 + quad * 4;
            #pragma unroll
            for (int u = 0; u < 4; u++) {
                int gn = n0 + wc * 64 + u * 16 + l16;
                #pragma unroll
                for (int r = 0; r < 4; r++)
                    fOut[(size_t)(gm0 + r) * N + gn] = acc[t][u][r];
            }
        }
    }
}

// ------------------------------- attention ----------------------------------
// Block: 64 q-rows (1 m-tile of 16 per wave, 4 waves), KV tiles of 64.
// qk: [4096, 2560] bf16 (Q pre-scaled | K).  vt: [(b*4+h)*128+d][2048] bf16.
// ao: [4096, 2048] bf16, cols hf*128+d.
// K/V staged via global_load_lds into UNPADDED LDS with source-side XOR
// swizzle (slot ^ (row&7)); all LDS b128 reads are <=2-way (free).
__global__ __launch_bounds__(256, 3)
void attn_kernel(const u16* __restrict__ qk, const u16* __restrict__ vt,
                 u16* __restrict__ ao)
{
    __shared__ __attribute__((aligned(16))) u16 Ks[64 * 128];   // 16 KB
    __shared__ __attribute__((aligned(16))) u16 Vs[128 * 64];   // 16 KB
    __shared__ __attribute__((aligned(16))) u16 Ps[4][16 * 72]; // per-wave P

    const int tid  = threadIdx.x;
    const int wave = tid >> 6, lane = tid & 63;
    const int quad = lane >> 4, l16 = lane & 15;
    const int bh = blockIdx.y;
    const int b = bh >> 4, hf = bh & 15, h = hf >> 2;
    const int i0 = blockIdx.x * 64 + wave * 16;   // this wave's 16 q-rows

    // Q fragments (A-operand: A[m=l16][k=quad*8+j], 4 k-chunks of 32)
    s8v aq[4];
    {
        const u16* qrow = qk + (size_t)(b * 2048 + i0 + l16) * 2560
                             + hf * 128 + quad * 8;
        #pragma unroll
        for (int c4 = 0; c4 < 4; c4++) aq[c4] = *(const s8v*)(qrow + c4 * 32);
    }

    float m_i[4], l_i[4];
    f4 o[8] = {};
    #pragma unroll
    for (int r = 0; r < 4; r++) { m_i[r] = -1e30f; l_i[r] = 0.f; }

    const u16* kbase = qk + (size_t)(b * 2048) * 2560 + 2048 + h * 128;
    const u16* vbase = vt + (size_t)((b * 4 + h) * 128) * 2048;
    u16* Pw = &Ps[wave][0];

    for (int s0 = 0; s0 < 2048; s0 += 64) {
        // stage K (64x128) and V^T (128x64) via global_load_lds, 16 chunks ea.
        #pragma unroll
        for (int i = 0; i < 4; i++) {
            const int c = wave + i * 4;               // wave-uniform 0..15
            {   // K chunk: 4 rows x 128 cols
                int kr = c * 4 + (lane >> 4);
                int sw = (lane & 15) ^ (kr & 7);
                GLD_LDS(kbase + (size_t)(s0 + kr) * 2560 + sw * 8, Ks + c * 512);
            }
            {   // V chunk: 8 rows x 64 cols
                int vd = c * 8 + (lane >> 3);
                int sw = (lane & 7) ^ (vd & 7);
                GLD_LDS(vbase + (size_t)vd * 2048 + s0 + sw * 8, Vs + c * 512);
            }
        }
        __syncthreads();

        // S = Q K^T : 4 col-groups of 16
        f4 sc[4] = {};
        #pragma unroll
        for (int c4 = 0; c4 < 4; c4++)
            #pragma unroll
            for (int cg = 0; cg < 4; cg++) {
                int n = cg * 16 + l16;
                s8v bk = *(const s8v*)(Ks + n * 128 + (((c4 * 4 + quad) ^ (n & 7)) * 8));
                sc[cg] = __builtin_amdgcn_mfma_f32_16x16x32_bf16(
                    aq[c4], bk, sc[cg], 0, 0, 0);
            }

        // online softmax: local max over 4 cgs, one 4-step butterfly per row
        float mx[4], al[4], rs[4];
        #pragma unroll
        for (int r = 0; r < 4; r++)
            mx[r] = fmaxf(fmaxf(sc[0][r], sc[1][r]), fmaxf(sc[2][r], sc[3][r]));
        #pragma unroll
        for (int off = 1; off < 16; off <<= 1)
            #pragma unroll
            for (int r = 0; r < 4; r++) mx[r] = fmaxf(mx[r], __shfl_xor(mx[r], off));
        #pragma unroll
        for (int r = 0; r < 4; r++) {
            float mn = fmaxf(m_i[r], mx[r]);
            al[r] = __expf(m_i[r] - mn);
            m_i[r] = mn;
            float e0 = __expf(sc[0][r] - mn), e1 = __expf(sc[1][r] - mn);
            float e2 = __expf(sc[2][r] - mn), e3 = __expf(sc[3][r] - mn);
            sc[0][r] = e0; sc[1][r] = e1; sc[2][r] = e2; sc[3][r] = e3;
            rs[r] = (e0 + e1) + (e2 + e3);
        }
        #pragma unroll
        for (int off = 1; off < 16; off <<= 1)
            #pragma unroll
            for (int r = 0; r < 4; r++) rs[r] += __shfl_xor(rs[r], off);
        f4 al4 = {al[0], al[1], al[2], al[3]};
        #pragma unroll
        for (int r = 0; r < 4; r++) l_i[r] = l_i[r] * al[r] + rs[r];
        #pragma unroll
        for (int ch = 0; ch < 8; ch++) o[ch] *= al4;

        // P: C-layout (row=quad*4+r, col=cg*16+l16) -> per-wave LDS (stride 72)
        #pragma unroll
        for (int cg = 0; cg < 4; cg++)
            #pragma unroll
            for (int r = 0; r < 4; r++)
                Pw[(quad * 4 + r) * 72 + cg * 16 + l16] = f2bf(sc[cg][r]);
        // same-wave DS ops are in-order: no barrier needed before re-read
        s8v ap0 = *(const s8v*)(Pw + l16 * 72 + quad * 8);
        s8v ap1 = *(const s8v*)(Pw + l16 * 72 + 32 + quad * 8);

        // O += P V : B rows are V^T rows (n = d), k = kv position
        #pragma unroll
        for (int ch = 0; ch < 8; ch++) {
            int n = ch * 16 + l16;
            s8v bv0 = *(const s8v*)(Vs + n * 64 + (((quad)     ^ (n & 7)) * 8));
            s8v bv1 = *(const s8v*)(Vs + n * 64 + (((4 + quad) ^ (n & 7)) * 8));
            o[ch] = __builtin_amdgcn_mfma_f32_16x16x32_bf16(ap0, bv0, o[ch], 0, 0, 0);
            o[ch] = __builtin_amdgcn_mfma_f32_16x16x32_bf16(ap1, bv1, o[ch], 0, 0, 0);
        }
        __syncthreads();   // protect Ks/Vs before next staging
    }

    #pragma unroll
    for (int r = 0; r < 4; r++) {
        float inv = 1.f / l_i[r];
        int gm = b * 2048 + i0 + quad * 4 + r;
        #pragma unroll
        for (int ch = 0; ch < 8; ch++)
            ao[(size_t)gm * 2048 + hf * 128 + ch * 16 + l16] = f2bf(o[ch][r] * inv);
    }
}

// ------------------------------- launcher -----------------------------------
extern "C" void kernel_launch(void* const* d_in, const int* in_sizes, int n_in,
                              void* d_out, int out_size, void* d_ws, size_t ws_size,
                              hipStream_t stream)
{
    const float* x  = (const float*)d_in[0];
    const float* Wq = (const float*)d_in[3];
    const float* Wk = (const float*)d_in[4];
    const float* Wv = (const float*)d_in[5];
    const float* Wo = (const float*)d_in[6];

    char* ws = (char*)d_ws;
    u16* xb   = (u16*)(ws);                 // 4096x2048
    u16* wqkv = (u16*)(ws + 16777216);      // 3072x2048
    u16* wo   = (u16*)(ws + 29360128);      // 2048x2048
    u16* qkb  = (u16*)(ws + 37748736);      // 4096x2560
    u16* vtb  = (u16*)(ws + 58720256);      // 2x4x128x2048
    u16* ao   = (u16*)(ws + 62914560);      // 4096x2048
    if (ws_size < 79691776u) return;

    cvt_kernel<<<8192, 256, 0, stream>>>(x,  xb,             2097152);
    cvt_kernel<<<4096, 256, 0, stream>>>(Wq, wqkv,           1048576);
    cvt_kernel<<<1024, 256, 0, stream>>>(Wk, wqkv + 4194304,  262144);
    cvt_kernel<<<1024, 256, 0, stream>>>(Wv, wqkv + 5242880,  262144);
    cvt_kernel<<<4096, 256, 0, stream>>>(Wo, wo,             1048576);

    gemm_bt<0><<<dim3(24, 32), 256, 0, stream>>>(xb, wqkv, 4096, 3072, 2048,
                                                 qkb, vtb, nullptr);
    attn_kernel<<<dim3(32, 32), 256, 0, stream>>>(qkb, vtb, ao);
    gemm_bt<1><<<dim3(16, 32), 256, 0, stream>>>(ao, wo, 4096, 2048, 2048,
                                                 nullptr, nullptr, (float*)d_out);
}

// Round 4
// 340.738 us; speedup vs baseline: 1.4051x; 1.1855x over previous
//
#include <hip/hip_runtime.h>
#include <stdint.h>

// ---------------------------------------------------------------------------
// GQA forward: y = OutProj( Attention( QKVProj(x) ) )
// B=2, S=2048, EMB=2048, NQH=16, HD=128, NKV=4, G=4. Non-causal softmax.
// R4: attention — M=2 (32 q-rows/wave, block=128 rows, grid 512 = 2 blk/CU,
//     no occupancy tail), row-sum l_i via MFMA ones-trick (9th channel),
//     max-reduce via DPP row_ror (VALU, off the LDS pipe).
// ---------------------------------------------------------------------------

typedef short s8v __attribute__((ext_vector_type(8)));   // 8 bf16 = 16 B
typedef float f4  __attribute__((ext_vector_type(4)));
typedef unsigned short u16;

#define GLD_LDS(g, l) __builtin_amdgcn_global_load_lds(                     \
    (const __attribute__((address_space(1))) void*)(g),                     \
    (__attribute__((address_space(3))) void*)(l), 16, 0, 0)

__device__ __forceinline__ u16 f2bf(float f) {
    union { float f; uint32_t u; } v; v.f = f;
    uint32_t u = v.u;
    return (u16)((u + 0x7fffu + ((u >> 16) & 1u)) >> 16);   // RNE
}

// max-reduce over the 16-lane DPP row via row_ror (pure VALU, no LDS pipe)
__device__ __forceinline__ float rowmax16(float x) {
    x = fmaxf(x, __int_as_float(__builtin_amdgcn_update_dpp(
        0, __float_as_int(x), 0x128, 0xf, 0xf, true)));   // ror:8
    x = fmaxf(x, __int_as_float(__builtin_amdgcn_update_dpp(
        0, __float_as_int(x), 0x124, 0xf, 0xf, true)));   // ror:4
    x = fmaxf(x, __int_as_float(__builtin_amdgcn_update_dpp(
        0, __float_as_int(x), 0x122, 0xf, 0xf, true)));   // ror:2
    x = fmaxf(x, __int_as_float(__builtin_amdgcn_update_dpp(
        0, __float_as_int(x), 0x121, 0xf, 0xf, true)));   // ror:1
    return x;
}

// --------------------------- fp32 -> bf16 cast ------------------------------
__global__ void cvt_kernel(const float* __restrict__ src, u16* __restrict__ dst, int n4) {
    int i = blockIdx.x * blockDim.x + threadIdx.x;
    if (i >= n4) return;
    float4 v = ((const float4*)src)[i];
    ushort4 o;
    o.x = f2bf(v.x); o.y = f2bf(v.y); o.z = f2bf(v.z); o.w = f2bf(v.w);
    ((ushort4*)dst)[i] = o;
}

// --------------------------- GEMM: C = A * B^T ------------------------------
// MODE 0: QKV epilogue -> qkOut [M,2560] (Q cols pre-scaled by 1/sqrt(128)),
//         V cols written transposed to vtOut [(b*4+h)*128+d][2048].
// MODE 1: fp32 epilogue -> fOut [M,N].
template<int MODE>
__global__ __launch_bounds__(256, 2)
void gemm_bt(const u16* __restrict__ A, const u16* __restrict__ Bm,
             int M, int N, int K,
             u16* __restrict__ qkOut, u16* __restrict__ vtOut,
             float* __restrict__ fOut)
{
    __shared__ __attribute__((aligned(16))) u16 As[128 * 32];
    __shared__ __attribute__((aligned(16))) u16 Bs[128 * 32];

    const int tid  = threadIdx.x;
    const int wave = tid >> 6, lane = tid & 63;
    const int quad = lane >> 4, l16 = lane & 15;
    const int wr = wave >> 1, wc = wave & 1;
    const int m0 = blockIdx.y * 128, n0 = blockIdx.x * 128;

    const int rowC = lane >> 2;
    const int slot = lane & 3;

    f4 acc[4][4] = {};

    for (int k0 = 0; k0 < K; k0 += 32) {
        #pragma unroll
        for (int i = 0; i < 4; i++) {
            const int c  = wave + i * 4;
            const int ch = c & 7;
            const int row = ch * 16 + rowC;
            const int glog = slot ^ (row & 3);
            const u16* gsrc = (c < 8)
                ? (A  + (size_t)(m0 + row) * K + k0 + glog * 8)
                : (Bm + (size_t)(n0 + row) * K + k0 + glog * 8);
            u16* lbase = (c < 8) ? (As + ch * 512) : (Bs + ch * 512);
            GLD_LDS(gsrc, lbase);
        }
        __syncthreads();

        s8v af[4], bfr[4];
        #pragma unroll
        for (int t = 0; t < 4; t++) {
            int row = wr * 64 + t * 16 + l16;
            af[t] = *(const s8v*)(As + row * 32 + ((quad ^ (row & 3)) * 8));
        }
        #pragma unroll
        for (int u = 0; u < 4; u++) {
            int row = wc * 64 + u * 16 + l16;
            bfr[u] = *(const s8v*)(Bs + row * 32 + ((quad ^ (row & 3)) * 8));
        }
        #pragma unroll
        for (int t = 0; t < 4; t++)
            #pragma unroll
            for (int u = 0; u < 4; u++)
                acc[t][u] = __builtin_amdgcn_mfma_f32_16x16x32_bf16(
                    af[t], bfr[u], acc[t][u], 0, 0, 0);
        __syncthreads();
    }

    if (MODE == 0) {
        if (n0 < 2560) {
            const float qs = (n0 < 2048) ? 0.08838834764831845f : 1.0f;
            #pragma unroll
            for (int t = 0; t < 4; t++) {
                int gm0 = m0 + wr * 64 + t * 16 + quad * 4;
                #pragma unroll
                for (int u = 0; u < 4; u++) {
                    int gn = n0 + wc * 64 + u * 16 + l16;
                    #pragma unroll
                    for (int r = 0; r < 4; r++)
                        qkOut[(size_t)(gm0 + r) * 2560 + gn] = f2bf(acc[t][u][r] * qs);
                }
            }
        } else {
            #pragma unroll
            for (int t = 0; t < 4; t++) {
                int gm0 = m0 + wr * 64 + t * 16 + quad * 4;
                int bb = gm0 >> 11, s = gm0 & 2047;
                #pragma unroll
                for (int u = 0; u < 4; u++) {
                    int gn = n0 + wc * 64 + u * 16 + l16;
                    int dd = gn - 2560;
                    ushort4 pk;
                    pk.x = f2bf(acc[t][u][0]); pk.y = f2bf(acc[t][u][1]);
                    pk.z = f2bf(acc[t][u][2]); pk.w = f2bf(acc[t][u][3]);
                    *(ushort4*)(vtOut +
                        ((size_t)(bb * 4 + (dd >> 7)) * 128 + (dd & 127)) * 2048 + s) = pk;
                }
            }
        }
    } else {
        #pragma unroll
        for (int t = 0; t < 4; t++) {
            int gm0 = m0 + wr * 64 + t * 16 + quad * 4;
            #pragma unroll
            for (int u = 0; u < 4; u++) {
                int gn = n0 + wc * 64 + u * 16 + l16;
                #pragma unroll
                for (int r = 0; r < 4; r++)
                    fOut[(size_t)(gm0 + r) * N + gn] = acc[t][u][r];
            }
        }
    }
}

// ------------------------------- attention ----------------------------------
// Block: 128 q-rows, 4 waves x (2 m-tiles of 16), KV tiles of 64.
// qk: [4096, 2560] bf16 (Q pre-scaled | K).  vt: [(b*4+h)*128+d][2048] bf16.
// ao: [4096, 2048] bf16, cols hf*128+d.
// l_i tracked as a 9th MFMA accumulator channel (P x ones).
__global__ __launch_bounds__(256, 2)
void attn_kernel(const u16* __restrict__ qk, const u16* __restrict__ vt,
                 u16* __restrict__ ao)
{
    __shared__ __attribute__((aligned(16))) u16 Ks[64 * 128];    // 16 KB
    __shared__ __attribute__((aligned(16))) u16 Vs[128 * 64];    // 16 KB
    __shared__ __attribute__((aligned(16))) u16 Ps[4][32 * 72];  // 18 KB

    const int tid  = threadIdx.x;
    const int wave = tid >> 6, lane = tid & 63;
    const int quad = lane >> 4, l16 = lane & 15;
    const int bh = blockIdx.y;
    const int b = bh >> 4, hf = bh & 15, h = hf >> 2;
    const int qrow0 = blockIdx.x * 128 + wave * 32;   // wave's 32 q-rows

    // Q fragments (A-operand), 2 m-tiles x 4 k-chunks
    s8v aq[2][4];
    #pragma unroll
    for (int mt = 0; mt < 2; mt++) {
        const u16* qrow = qk + (size_t)(b * 2048 + qrow0 + mt * 16 + l16) * 2560
                             + hf * 128 + quad * 8;
        #pragma unroll
        for (int c4 = 0; c4 < 4; c4++) aq[mt][c4] = *(const s8v*)(qrow + c4 * 32);
    }

    s8v ones;
    #pragma unroll
    for (int j = 0; j < 8; j++) ones[j] = (short)0x3F80;   // bf16 1.0

    float m_i[2][4];
    f4 o[2][9] = {};          // 8 d-channels + [8] = row-sum (l_i)
    #pragma unroll
    for (int mt = 0; mt < 2; mt++)
        #pragma unroll
        for (int r = 0; r < 4; r++) m_i[mt][r] = -1e30f;

    const u16* kbase = qk + (size_t)(b * 2048) * 2560 + 2048 + h * 128;
    const u16* vbase = vt + (size_t)((b * 4 + h) * 128) * 2048;
    u16* Pw = &Ps[wave][0];

    for (int s0 = 0; s0 < 2048; s0 += 64) {
        // stage K (64x128) and V^T (128x64) via global_load_lds, 16 chunks ea.
        #pragma unroll
        for (int i = 0; i < 4; i++) {
            const int c = wave + i * 4;               // wave-uniform 0..15
            {   // K chunk: 4 rows x 128 cols
                int kr = c * 4 + (lane >> 4);
                int sw = (lane & 15) ^ (kr & 7);
                GLD_LDS(kbase + (size_t)(s0 + kr) * 2560 + sw * 8, Ks + c * 512);
            }
            {   // V chunk: 8 rows x 64 cols
                int vd = c * 8 + (lane >> 3);
                int sw = (lane & 7) ^ (vd & 7);
                GLD_LDS(vbase + (size_t)vd * 2048 + s0 + sw * 8, Vs + c * 512);
            }
        }
        __syncthreads();

        // S = Q K^T : 4 col-groups of 16, 2 m-tiles
        f4 sc[2][4] = {};
        #pragma unroll
        for (int c4 = 0; c4 < 4; c4++)
            #pragma unroll
            for (int cg = 0; cg < 4; cg++) {
                int n = cg * 16 + l16;
                s8v bk = *(const s8v*)(Ks + n * 128 + (((c4 * 4 + quad) ^ (n & 7)) * 8));
                #pragma unroll
                for (int mt = 0; mt < 2; mt++)
                    sc[mt][cg] = __builtin_amdgcn_mfma_f32_16x16x32_bf16(
                        aq[mt][c4], bk, sc[mt][cg], 0, 0, 0);
            }

        // online softmax: DPP row-max, exp, rescale; row-sum comes via MFMA
        #pragma unroll
        for (int mt = 0; mt < 2; mt++) {
            float al[4];
            #pragma unroll
            for (int r = 0; r < 4; r++) {
                float mx = fmaxf(fmaxf(sc[mt][0][r], sc[mt][1][r]),
                                 fmaxf(sc[mt][2][r], sc[mt][3][r]));
                mx = rowmax16(mx);
                float mn = fmaxf(m_i[mt][r], mx);
                al[r] = __expf(m_i[mt][r] - mn);
                m_i[mt][r] = mn;
                #pragma unroll
                for (int cg = 0; cg < 4; cg++)
                    sc[mt][cg][r] = __expf(sc[mt][cg][r] - mn);
            }
            f4 al4 = {al[0], al[1], al[2], al[3]};
            #pragma unroll
            for (int ch = 0; ch < 9; ch++) o[mt][ch] *= al4;
            // P: C-layout (row=quad*4+r, col=cg*16+l16) -> per-wave LDS
            #pragma unroll
            for (int cg = 0; cg < 4; cg++)
                #pragma unroll
                for (int r = 0; r < 4; r++)
                    Pw[(mt * 16 + quad * 4 + r) * 72 + cg * 16 + l16] = f2bf(sc[mt][cg][r]);
        }
        // same-wave DS in-order: safe to re-read without barrier
        s8v ap[2][2];
        #pragma unroll
        for (int mt = 0; mt < 2; mt++)
            #pragma unroll
            for (int kc = 0; kc < 2; kc++)
                ap[mt][kc] = *(const s8v*)(Pw + (mt * 16 + l16) * 72 + kc * 32 + quad * 8);

        // O += P V : V^T rows (n = d) as B; 2 k-chunks of 32
        #pragma unroll
        for (int ch = 0; ch < 8; ch++) {
            int n = ch * 16 + l16;
            s8v bv0 = *(const s8v*)(Vs + n * 64 + (((quad)     ^ (n & 7)) * 8));
            s8v bv1 = *(const s8v*)(Vs + n * 64 + (((4 + quad) ^ (n & 7)) * 8));
            #pragma unroll
            for (int mt = 0; mt < 2; mt++) {
                o[mt][ch] = __builtin_amdgcn_mfma_f32_16x16x32_bf16(ap[mt][0], bv0, o[mt][ch], 0, 0, 0);
                o[mt][ch] = __builtin_amdgcn_mfma_f32_16x16x32_bf16(ap[mt][1], bv1, o[mt][ch], 0, 0, 0);
            }
        }
        // l_i: row-sum of P via ones-fragment MFMA
        #pragma unroll
        for (int mt = 0; mt < 2; mt++) {
            o[mt][8] = __builtin_amdgcn_mfma_f32_16x16x32_bf16(ap[mt][0], ones, o[mt][8], 0, 0, 0);
            o[mt][8] = __builtin_amdgcn_mfma_f32_16x16x32_bf16(ap[mt][1], ones, o[mt][8], 0, 0, 0);
        }
        __syncthreads();   // protect Ks/Vs before next staging
    }

    #pragma unroll
    for (int mt = 0; mt < 2; mt++)
        #pragma unroll
        for (int r = 0; r < 4; r++) {
            float inv = 1.f / o[mt][8][r];   // all cols of l-channel are equal
            int gm = b * 2048 + qrow0 + mt * 16 + quad * 4 + r;
            #pragma unroll
            for (int ch = 0; ch < 8; ch++)
                ao[(size_t)gm * 2048 + hf * 128 + ch * 16 + l16] = f2bf(o[mt][ch][r] * inv);
        }
}

// ------------------------------- launcher -----------------------------------
extern "C" void kernel_launch(void* const* d_in, const int* in_sizes, int n_in,
                              void* d_out, int out_size, void* d_ws, size_t ws_size,
                              hipStream_t stream)
{
    const float* x  = (const float*)d_in[0];
    const float* Wq = (const float*)d_in[3];
    const float* Wk = (const float*)d_in[4];
    const float* Wv = (const float*)d_in[5];
    const float* Wo = (const float*)d_in[6];

    char* ws = (char*)d_ws;
    u16* xb   = (u16*)(ws);                 // 4096x2048
    u16* wqkv = (u16*)(ws + 16777216);      // 3072x2048
    u16* wo   = (u16*)(ws + 29360128);      // 2048x2048
    u16* qkb  = (u16*)(ws + 37748736);      // 4096x2560
    u16* vtb  = (u16*)(ws + 58720256);      // 2x4x128x2048
    u16* ao   = (u16*)(ws + 62914560);      // 4096x2048
    if (ws_size < 79691776u) return;

    cvt_kernel<<<8192, 256, 0, stream>>>(x,  xb,             2097152);
    cvt_kernel<<<4096, 256, 0, stream>>>(Wq, wqkv,           1048576);
    cvt_kernel<<<1024, 256, 0, stream>>>(Wk, wqkv + 4194304,  262144);
    cvt_kernel<<<1024, 256, 0, stream>>>(Wv, wqkv + 5242880,  262144);
    cvt_kernel<<<4096, 256, 0, stream>>>(Wo, wo,             1048576);

    gemm_bt<0><<<dim3(24, 32), 256, 0, stream>>>(xb, wqkv, 4096, 3072, 2048,
                                                 qkb, vtb, nullptr);
    attn_kernel<<<dim3(16, 32), 256, 0, stream>>>(qkb, vtb, ao);
    gemm_bt<1><<<dim3(16, 32), 256, 0, stream>>>(ao, wo, 4096, 2048, 2048,
                                                 nullptr, nullptr, (float*)d_out);
}